// Round 1
// baseline (264.098 us; speedup 1.0000x reference)
//
#include <hip/hip_runtime.h>
#include <math.h>

#define B  32
#define P  128
#define L  19
#define H  256
#define HA 128
#define SLOPE 0.2f
#define NEGV -1000000000.0f
#define PL (P*L)          /* 2432 */
#define TI 8
#define NTILE (P/TI)      /* 16 */
#define NBLK (B*NTILE)    /* 512 */

// ---------------------------------------------------------------------------
// Kernel 0: detect mask buffer layout. jax bool may arrive as 1-byte bools or
// as int32 0/1. If int32 (little-endian), bytes at 4k+1..4k+3 are all zero.
// Random 0/1 bytes make "all zero" impossible for the bool layout.
// Reads only the first 4096 bytes = min(bool 4096B, int32 16384B). Safe.
// ---------------------------------------------------------------------------
__global__ void sniff_mask(const unsigned char* __restrict__ m, int* flag) {
    __shared__ int s;
    if (threadIdx.x == 0) s = 0;
    __syncthreads();
    int acc = 0;
    for (int k = threadIdx.x; k < 1024; k += 256)
        acc |= m[4*k+1] | m[4*k+2] | m[4*k+3];
    if (acc) atomicOr(&s, 1);
    __syncthreads();
    if (threadIdx.x == 0) flag[0] = s;   // 1 => byte layout, 0 => int32 layout
}

// ---------------------------------------------------------------------------
// Kernel 1: u1[h] = sum_a W1[a,h]*W2[a],  u2[h] = sum_a W1[a,h]*W2[HA+a]
// ---------------------------------------------------------------------------
__global__ void compute_u(const float* __restrict__ W1,
                          const float* __restrict__ W2,
                          float* __restrict__ u) {
    int h = threadIdx.x;             // 256 threads
    float s1 = 0.f, s2 = 0.f;
    for (int a = 0; a < HA; ++a) {
        float w = W1[a*H + h];
        s1 += w * W2[a];
        s2 += w * W2[HA + a];
    }
    u[h]     = s1;
    u[H + h] = s2;
}

// ---------------------------------------------------------------------------
// Kernel 2: e1[row]=agents[row,:]·u1, e2[row]=agents[row,:]·u2, row=(b,p,l)
// One wave (64 lanes) per row; float4 loads; shuffle reduce.
// ---------------------------------------------------------------------------
__global__ __launch_bounds__(256) void compute_e(const float* __restrict__ A,
                                                 const float* __restrict__ u,
                                                 float* __restrict__ e1,
                                                 float* __restrict__ e2) {
    int wid  = threadIdx.x >> 6;
    int lane = threadIdx.x & 63;
    int row  = blockIdx.x * 4 + wid;            // < 77824
    const float4 a  = *(const float4*)(A + (size_t)row*H + lane*4);
    const float4 u1 = *(const float4*)(u + lane*4);
    const float4 u2 = *(const float4*)(u + H + lane*4);
    float s1 = a.x*u1.x + a.y*u1.y + a.z*u1.z + a.w*u1.w;
    float s2 = a.x*u2.x + a.y*u2.y + a.z*u2.z + a.w*u2.w;
    #pragma unroll
    for (int off = 32; off; off >>= 1) {
        s1 += __shfl_down(s1, off, 64);
        s2 += __shfl_down(s2, off, 64);
    }
    if (lane == 0) { e1[row] = s1; e2[row] = s2; }
}

// ---------------------------------------------------------------------------
// Kernel 3: per (b, i-tile of 8): softmax weights in LDS, then
// out[b,i,l,h] = sigmoid(sum_j w[j,l,ti] * agents[b,j,l,h])
// ---------------------------------------------------------------------------
__global__ __launch_bounds__(256) void gat_main(
    const float* __restrict__ A,     // agents (B,P,L,H)
    const float* __restrict__ adj,   // (B,P,P,L)
    const void*  __restrict__ maskp,
    const float* __restrict__ e1,
    const float* __restrict__ e2,
    const int*   __restrict__ flagp,
    float* __restrict__ out)
{
    __shared__ float w_lds[PL*TI];   // [p*L+l][ti]  77824 B
    __shared__ float e2s[PL];        // [p*L+l]       9728 B
    __shared__ float e1s[TI*L];      // [ti*L+l]       608 B
    __shared__ int   msk[P];

    // XCD-aware swizzle: blocks of the same b land on the same XCD so
    // agents[b] (2.5 MB) stays L2-resident across its 16 i-tiles.
    int w     = blockIdx.x;
    int xcd   = w & 7;
    int idx   = w >> 3;
    int itile = idx & (NTILE-1);
    int bg    = idx >> 4;            // 0..3
    int b     = bg*8 + xcd;
    int i0    = itile*TI;
    int tid   = threadIdx.x;

    int flag = flagp[0];
    if (tid < P) {
        int mv;
        if (flag) mv = (((const unsigned char*)maskp)[b*P + tid] != 0);
        else      mv = (((const int*)maskp)[b*P + tid] != 0);
        msk[tid] = mv;
    }
    for (int q = tid; q < PL; q += 256) e2s[q] = e2[b*PL + q];
    if (tid < TI*L) e1s[tid] = e1[(b*P + i0)*L + tid];
    #pragma unroll
    for (int ti = 0; ti < TI; ++ti) {
        const float* ap = adj + (size_t)(b*P + i0 + ti) * PL;
        for (int q = tid; q < PL; q += 256)
            w_lds[q*TI + ti] = (ap[q] > 0.0f) ? 1.0f : 0.0f;
    }
    __syncthreads();

    // masked leaky-relu softmax over j, one thread per (ti,l) row
    if (tid < TI*L) {
        int l = tid % L;
        int ti = tid / L; (void)ti;
        float e1v = e1s[tid];
        float m = -INFINITY;
        for (int j = 0; j < P; ++j) {
            float s = e1v + e2s[j*L + l];
            s = (s > 0.f) ? s : SLOPE*s;
            if (msk[j]) s = NEGV;
            m = fmaxf(m, s);
        }
        float sum = 0.f;
        for (int j = 0; j < P; ++j) {
            float s = e1v + e2s[j*L + l];
            s = (s > 0.f) ? s : SLOPE*s;
            if (msk[j]) s = NEGV;
            float ex = __expf(s - m);
            sum += ex;
            w_lds[(j*L + l)*TI + (tid/L)] *= ex;
        }
        float inv = 1.f / sum;
        for (int j = 0; j < P; ++j)
            w_lds[(j*L + l)*TI + (tid/L)] *= inv;
    }
    __syncthreads();

    // weighted sum: 4 groups of 64 lanes; group g owns l = g, g+4, ...
    // each lane owns 4 h-columns (float4), all 8 i's of the tile.
    int g    = tid >> 6;
    int lane = tid & 63;
    int h4   = lane * 4;
    for (int l = g; l < L; l += 4) {
        float4 acc[TI];
        #pragma unroll
        for (int t = 0; t < TI; ++t) acc[t] = make_float4(0.f,0.f,0.f,0.f);
        const float* ap = A + ((size_t)(b*P)*L + l)*H + h4;
        const float* wp = w_lds + l*TI;
        #pragma unroll 4
        for (int j = 0; j < P; ++j) {
            float4 a = *(const float4*)(ap + (size_t)j*(L*H));
            const float4* wv = (const float4*)(wp + j*(L*TI));
            float4 w0 = wv[0], w1 = wv[1];
            acc[0].x += w0.x*a.x; acc[0].y += w0.x*a.y; acc[0].z += w0.x*a.z; acc[0].w += w0.x*a.w;
            acc[1].x += w0.y*a.x; acc[1].y += w0.y*a.y; acc[1].z += w0.y*a.z; acc[1].w += w0.y*a.w;
            acc[2].x += w0.z*a.x; acc[2].y += w0.z*a.y; acc[2].z += w0.z*a.z; acc[2].w += w0.z*a.w;
            acc[3].x += w0.w*a.x; acc[3].y += w0.w*a.y; acc[3].z += w0.w*a.z; acc[3].w += w0.w*a.w;
            acc[4].x += w1.x*a.x; acc[4].y += w1.x*a.y; acc[4].z += w1.x*a.z; acc[4].w += w1.x*a.w;
            acc[5].x += w1.y*a.x; acc[5].y += w1.y*a.y; acc[5].z += w1.y*a.z; acc[5].w += w1.y*a.w;
            acc[6].x += w1.z*a.x; acc[6].y += w1.z*a.y; acc[6].z += w1.z*a.z; acc[6].w += w1.z*a.w;
            acc[7].x += w1.w*a.x; acc[7].y += w1.w*a.y; acc[7].z += w1.w*a.z; acc[7].w += w1.w*a.w;
        }
        #pragma unroll
        for (int t = 0; t < TI; ++t) {
            float4 o;
            o.x = 1.f/(1.f + __expf(-acc[t].x));
            o.y = 1.f/(1.f + __expf(-acc[t].y));
            o.z = 1.f/(1.f + __expf(-acc[t].z));
            o.w = 1.f/(1.f + __expf(-acc[t].w));
            *(float4*)(out + ((size_t)(b*P + i0 + t)*L + l)*H + h4) = o;
        }
    }
}

extern "C" void kernel_launch(void* const* d_in, const int* in_sizes, int n_in,
                              void* d_out, int out_size, void* d_ws, size_t ws_size,
                              hipStream_t stream) {
    const float* agents = (const float*)d_in[0];
    const float* adj    = (const float*)d_in[1];
    const void*  mask   = d_in[2];
    const float* W1     = (const float*)d_in[3];
    const float* W2     = (const float*)d_in[4];
    float* out = (float*)d_out;

    int*   flag = (int*)d_ws;
    float* u    = (float*)d_ws + 16;          // 64 B in
    float* e1   = u + 2*H;                    // 512 floats for u1|u2
    float* e2   = e1 + B*P*L;                 // 77824 floats each

    sniff_mask<<<1, 256, 0, stream>>>((const unsigned char*)mask, flag);
    compute_u <<<1, 256, 0, stream>>>(W1, W2, u);
    compute_e <<<(B*P*L)/4, 256, 0, stream>>>(agents, u, e1, e2);
    gat_main  <<<NBLK, 256, 0, stream>>>(agents, adj, mask, e1, e2, flag, out);
}

// Round 2
// 144.914 us; speedup vs baseline: 1.8224x; 1.8224x over previous
//
#include <hip/hip_runtime.h>
#include <math.h>

#define B  32
#define P  128
#define L  19
#define H  256
#define HA 128
#define SLOPE 0.2f
#define PL (P*L)          /* 2432 */
#define TI 8
#define NTILE (P/TI)      /* 16 */
#define NBLK (B*NTILE)    /* 512 */

__device__ inline unsigned short f32_to_bf16(float x) {
    unsigned u = __builtin_bit_cast(unsigned, x);
    unsigned r = (u + 0x7fffu + ((u >> 16) & 1u)) >> 16;
    return (unsigned short)r;
}
__device__ inline float bf16_lo(unsigned u) {   // low ushort -> f32
    return __builtin_bit_cast(float, u << 16);
}
__device__ inline float bf16_hi(unsigned u) {   // high ushort -> f32
    return __builtin_bit_cast(float, u & 0xffff0000u);
}

// ---------------------------------------------------------------------------
// Kernel 0: detect mask buffer layout (1-byte bool vs int32 0/1).
// ---------------------------------------------------------------------------
__global__ void sniff_mask(const unsigned char* __restrict__ m, int* flag) {
    __shared__ int s;
    if (threadIdx.x == 0) s = 0;
    __syncthreads();
    int acc = 0;
    for (int k = threadIdx.x; k < 1024; k += 256)
        acc |= m[4*k+1] | m[4*k+2] | m[4*k+3];
    if (acc) atomicOr(&s, 1);
    __syncthreads();
    if (threadIdx.x == 0) flag[0] = s;   // 1 => byte layout, 0 => int32 layout
}

// ---------------------------------------------------------------------------
// Kernel 1: u1[h] = sum_a W1[a,h]*W2[a],  u2[h] = sum_a W1[a,h]*W2[HA+a]
// ---------------------------------------------------------------------------
__global__ void compute_u(const float* __restrict__ W1,
                          const float* __restrict__ W2,
                          float* __restrict__ u) {
    int h = threadIdx.x;
    float s1 = 0.f, s2 = 0.f;
    for (int a = 0; a < HA; ++a) {
        float w = W1[a*H + h];
        s1 += w * W2[a];
        s2 += w * W2[HA + a];
    }
    u[h]     = s1;
    u[H + h] = s2;
}

// ---------------------------------------------------------------------------
// Kernel 2: e1[row]=agents[row,:]·u1, e2[row]=agents[row,:]·u2
// ---------------------------------------------------------------------------
__global__ __launch_bounds__(256) void compute_e(const float* __restrict__ A,
                                                 const float* __restrict__ u,
                                                 float* __restrict__ e1,
                                                 float* __restrict__ e2) {
    int wid  = threadIdx.x >> 6;
    int lane = threadIdx.x & 63;
    int row  = blockIdx.x * 4 + wid;
    const float4 a  = *(const float4*)(A + (size_t)row*H + lane*4);
    const float4 u1 = *(const float4*)(u + lane*4);
    const float4 u2 = *(const float4*)(u + H + lane*4);
    float s1 = a.x*u1.x + a.y*u1.y + a.z*u1.z + a.w*u1.w;
    float s2 = a.x*u2.x + a.y*u2.y + a.z*u2.z + a.w*u2.w;
    #pragma unroll
    for (int off = 32; off; off >>= 1) {
        s1 += __shfl_down(s1, off, 64);
        s2 += __shfl_down(s2, off, 64);
    }
    if (lane == 0) { e1[row] = s1; e2[row] = s2; }
}

// ---------------------------------------------------------------------------
// Kernel 3: per (b, 8-row i-tile).
// Phase A: stage adjmask (bf16 0/1, packed b128 writes), e2, e1, mask.
// Phase B: M2[l] = max over unmasked j of e2[j,l]   (closed-form row max,
//          valid because leaky_relu is monotone increasing).
// Phase C: single softmax pass: w = adjbit ? bf16(exp(leaky(e1+e2)-m)) : 0,
//          sum accumulated; 1/sum deferred to epilogue (linearity).
// Phase D: out[i,l,h] = sigmoid(inv * sum_j w[j,l,ti] * agents[b,j,l,h])
// LDS ~50 KB -> 3 blocks/CU.
// ---------------------------------------------------------------------------
__global__ __launch_bounds__(256, 3) void gat_main(
    const float* __restrict__ A,
    const float* __restrict__ adj,
    const void*  __restrict__ maskp,
    const float* __restrict__ e1,
    const float* __restrict__ e2,
    const int*   __restrict__ flagp,
    float* __restrict__ out)
{
    __shared__ unsigned short w_lds[PL*TI];  // bf16 [q=p*L+l][ti]  38912 B
    __shared__ float e2s[PL];                //  9728 B
    __shared__ float e1s[TI*L];
    __shared__ float invs[TI*L];
    __shared__ float M2[L];
    __shared__ int   msk[P];

    // XCD swizzle: 16 i-tiles of the same b stay on one XCD (agents[b] 2.5MB
    // vs 4MB XCD L2).
    int w     = blockIdx.x;
    int xcd   = w & 7;
    int idx   = w >> 3;
    int itile = idx & (NTILE-1);
    int bg    = idx >> 4;
    int b     = bg*8 + xcd;
    int i0    = itile*TI;
    int tid   = threadIdx.x;

    // ---- Phase A: staging
    int flag = flagp[0];
    if (tid < P) {
        int mv;
        if (flag) mv = (((const unsigned char*)maskp)[b*P + tid] != 0);
        else      mv = (((const int*)maskp)[b*P + tid] != 0);
        msk[tid] = mv;
    }
    for (int q = tid; q < PL; q += 256) e2s[q] = e2[b*PL + q];
    if (tid < TI*L) e1s[tid] = e1[(b*P + i0)*L + tid];

    for (int q = tid; q < PL; q += 256) {
        const float* ap = adj + (size_t)(b*P + i0)*PL + q;
        uint4 wv;
        unsigned short* wp = (unsigned short*)&wv;
        #pragma unroll
        for (int ti = 0; ti < TI; ++ti)
            wp[ti] = (ap[(size_t)ti*PL] > 0.0f) ? (unsigned short)0x3f80 : (unsigned short)0;
        *(uint4*)&w_lds[q*TI] = wv;          // contiguous 16B/lane: conflict-free
    }
    __syncthreads();

    // ---- Phase B: per-l max of e2 over unmasked j
    if (tid < L) {
        float mx = -INFINITY;
        for (int j = 0; j < P; ++j) {
            float v = msk[j] ? -INFINITY : e2s[j*L + tid];
            mx = fmaxf(mx, v);
        }
        M2[tid] = mx;
    }
    __syncthreads();

    // ---- Phase C: single pass softmax (max closed-form, inv deferred)
    if (tid < TI*L) {
        int l  = tid % L;
        int ti = tid / L;
        float e1v = e1s[tid];
        float s0  = e1v + M2[l];
        float m   = fmaxf(s0, SLOPE*s0);     // leaky(e1 + M2) == row max
        float sum = 0.f;
        for (int j = 0; j < P; ++j) {
            float s = e1v + e2s[j*L + l];
            s = fmaxf(s, SLOPE*s);
            float ex = msk[j] ? 0.f : __expf(s - m);
            sum += ex;
            int a = (j*L + l)*TI + ti;
            unsigned short adjbit = w_lds[a];
            w_lds[a] = adjbit ? f32_to_bf16(ex) : (unsigned short)0;
        }
        invs[tid] = 1.f / sum;
    }
    __syncthreads();

    // ---- Phase D: weighted sum. 4 l-groups x 64 lanes; lane owns 4 h.
    int g    = tid >> 6;
    int lane = tid & 63;
    int h4   = lane * 4;
    const uint4* wq_base = (const uint4*)w_lds;   // element q = p*L+l (16B each)
    for (int l = g; l < L; l += 4) {
        float4 acc[TI];
        #pragma unroll
        for (int t = 0; t < TI; ++t) acc[t] = make_float4(0.f,0.f,0.f,0.f);
        const float* ap = A + ((size_t)(b*P)*L + l)*H + h4;
        const uint4* wq = wq_base + l;
        #pragma unroll 4
        for (int j = 0; j < P; ++j) {
            float4 a = *(const float4*)(ap + (size_t)j*(L*H));
            uint4 wv = wq[j*L];               // broadcast read, conflict-free
            float w0 = bf16_lo(wv.x), w1 = bf16_hi(wv.x);
            float w2 = bf16_lo(wv.y), w3 = bf16_hi(wv.y);
            float w4 = bf16_lo(wv.z), w5 = bf16_hi(wv.z);
            float w6 = bf16_lo(wv.w), w7 = bf16_hi(wv.w);
            acc[0].x += w0*a.x; acc[0].y += w0*a.y; acc[0].z += w0*a.z; acc[0].w += w0*a.w;
            acc[1].x += w1*a.x; acc[1].y += w1*a.y; acc[1].z += w1*a.z; acc[1].w += w1*a.w;
            acc[2].x += w2*a.x; acc[2].y += w2*a.y; acc[2].z += w2*a.z; acc[2].w += w2*a.w;
            acc[3].x += w3*a.x; acc[3].y += w3*a.y; acc[3].z += w3*a.z; acc[3].w += w3*a.w;
            acc[4].x += w4*a.x; acc[4].y += w4*a.y; acc[4].z += w4*a.z; acc[4].w += w4*a.w;
            acc[5].x += w5*a.x; acc[5].y += w5*a.y; acc[5].z += w5*a.z; acc[5].w += w5*a.w;
            acc[6].x += w6*a.x; acc[6].y += w6*a.y; acc[6].z += w6*a.z; acc[6].w += w6*a.w;
            acc[7].x += w7*a.x; acc[7].y += w7*a.y; acc[7].z += w7*a.z; acc[7].w += w7*a.w;
        }
        #pragma unroll
        for (int t = 0; t < TI; ++t) {
            float inv = invs[t*L + l];
            float4 o;
            o.x = 1.f/(1.f + __expf(-acc[t].x*inv));
            o.y = 1.f/(1.f + __expf(-acc[t].y*inv));
            o.z = 1.f/(1.f + __expf(-acc[t].z*inv));
            o.w = 1.f/(1.f + __expf(-acc[t].w*inv));
            *(float4*)(out + ((size_t)(b*P + i0 + t)*L + l)*H + h4) = o;
        }
    }
}

extern "C" void kernel_launch(void* const* d_in, const int* in_sizes, int n_in,
                              void* d_out, int out_size, void* d_ws, size_t ws_size,
                              hipStream_t stream) {
    const float* agents = (const float*)d_in[0];
    const float* adj    = (const float*)d_in[1];
    const void*  mask   = d_in[2];
    const float* W1     = (const float*)d_in[3];
    const float* W2     = (const float*)d_in[4];
    float* out = (float*)d_out;

    int*   flag = (int*)d_ws;
    float* u    = (float*)d_ws + 16;
    float* e1   = u + 2*H;
    float* e2   = e1 + B*P*L;

    sniff_mask<<<1, 256, 0, stream>>>((const unsigned char*)mask, flag);
    compute_u <<<1, 256, 0, stream>>>(W1, W2, u);
    compute_e <<<(B*P*L)/4, 256, 0, stream>>>(agents, u, e1, e2);
    gat_main  <<<NBLK, 256, 0, stream>>>(agents, adj, mask, e1, e2, flag, out);
}

// Round 3
// 144.270 us; speedup vs baseline: 1.8306x; 1.0045x over previous
//
#include <hip/hip_runtime.h>
#include <math.h>

#define B  32
#define P  128
#define L  19
#define H  256
#define SLOPE 0.2f
#define PL (P*L)          /* 2432 */
#define TI 8
#define NTILE (P/TI)      /* 16 */
#define NLMAX 5
#define WROW 1028         /* 128*8 + 4 pad floats: l-slice stride, bank-skewed */
#define NBLK (B*NTILE*4)  /* 2048 */

// ---------------------------------------------------------------------------
// Kernel 0: detect mask buffer layout (1-byte bool vs int32 0/1).
// ---------------------------------------------------------------------------
__global__ void sniff_mask(const unsigned char* __restrict__ m, int* flag) {
    __shared__ int s;
    if (threadIdx.x == 0) s = 0;
    __syncthreads();
    int acc = 0;
    for (int k = threadIdx.x; k < 1024; k += 256)
        acc |= m[4*k+1] | m[4*k+2] | m[4*k+3];
    if (acc) atomicOr(&s, 1);
    __syncthreads();
    if (threadIdx.x == 0) flag[0] = s;   // 1 => byte layout, 0 => int32 layout
}

// ---------------------------------------------------------------------------
// Kernel 1: u1[h] = sum_a W1[a,h]*W2[a],  u2[h] = sum_a W1[a,h]*W2[HA+a]
// ---------------------------------------------------------------------------
__global__ void compute_u(const float* __restrict__ W1,
                          const float* __restrict__ W2,
                          float* __restrict__ u) {
    int h = threadIdx.x;
    float s1 = 0.f, s2 = 0.f;
    for (int a = 0; a < 128; ++a) {
        float w = W1[a*H + h];
        s1 += w * W2[a];
        s2 += w * W2[128 + a];
    }
    u[h]     = s1;
    u[H + h] = s2;
}

// ---------------------------------------------------------------------------
// Kernel 2: e1[row]=agents[row,:]·u1, e2[row]=agents[row,:]·u2
// ---------------------------------------------------------------------------
__global__ __launch_bounds__(256) void compute_e(const float* __restrict__ A,
                                                 const float* __restrict__ u,
                                                 float* __restrict__ e1,
                                                 float* __restrict__ e2) {
    int wid  = threadIdx.x >> 6;
    int lane = threadIdx.x & 63;
    int row  = blockIdx.x * 4 + wid;
    const float4 a  = *(const float4*)(A + (size_t)row*H + lane*4);
    const float4 u1 = *(const float4*)(u + lane*4);
    const float4 u2 = *(const float4*)(u + H + lane*4);
    float s1 = a.x*u1.x + a.y*u1.y + a.z*u1.z + a.w*u1.w;
    float s2 = a.x*u2.x + a.y*u2.y + a.z*u2.z + a.w*u2.w;
    #pragma unroll
    for (int off = 32; off; off >>= 1) {
        s1 += __shfl_down(s1, off, 64);
        s2 += __shfl_down(s2, off, 64);
    }
    if (lane == 0) { e1[row] = s1; e2[row] = s2; }
}

// ---------------------------------------------------------------------------
// Kernel 3: block = (b, 8-row i-tile, l%4 slice). NL = 5 (or 4 for lpar==3).
// LDS ~25 KB -> 6 blocks/CU -> 24 waves/CU.
// Phase A: stage adjbit (f32 0/1), e2 slice, e1 slice, mask.
// Phase B: M2[li] = max_j unmasked e2  (closed-form row max via monotone leaky)
// Phase C: 4 waves x 32-j chunks: w = adjbit * exp(leaky(e1+e2)-m); partial
//          sums -> invs (1/sum deferred to epilogue by linearity).
// Phase D: per (l, h-half) unit: lane owns 2 h; acc[8] float2; 16 FMA/j.
// ---------------------------------------------------------------------------
__global__ __launch_bounds__(256, 6) void gat_main(
    const float* __restrict__ A,
    const float* __restrict__ adj,
    const void*  __restrict__ maskp,
    const float* __restrict__ e1,
    const float* __restrict__ e2,
    const int*   __restrict__ flagp,
    float* __restrict__ out)
{
    __shared__ float w_lds[NLMAX*WROW];      // [li][j*8+ti] (+4 pad)  20560 B
    __shared__ float e2s[P*NLMAX];           // [j*5+li]                2560 B
    __shared__ float e1s[TI*NLMAX];          // [li*8+ti]
    __shared__ float invs[TI*NLMAX];
    __shared__ float M2[NLMAX];
    __shared__ float psum[4*TI*NLMAX];
    __shared__ int   msk[P];

    // XCD swizzle: all blocks of one b share an XCD (agents[b] L2-resident)
    int w     = blockIdx.x;
    int xcd   = w & 7;
    int idx   = w >> 3;
    int lpar  = idx & 3;
    int itile = (idx >> 2) & (NTILE-1);
    int bg    = idx >> 6;                    // 0..3
    int b     = bg*8 + xcd;
    int i0    = itile*TI;
    int tid   = threadIdx.x;
    int NL    = (lpar < 3) ? 5 : 4;

    // ---- Phase A: staging
    int flag = flagp[0];
    if (tid < P) {
        int mv;
        if (flag) mv = (((const unsigned char*)maskp)[b*P + tid] != 0);
        else      mv = (((const int*)maskp)[b*P + tid] != 0);
        msk[tid] = mv;
    }
    for (int q = tid; q < P*NLMAX; q += 256) {
        int j = q / NLMAX, li = q % NLMAX;
        if (li < NL) e2s[q] = e2[b*PL + j*L + li*4 + lpar];
    }
    if (tid < TI*NLMAX) {
        int ti = tid & 7, li = tid >> 3;
        if (li < NL) e1s[tid] = e1[(b*P + i0 + ti)*L + li*4 + lpar];
    }
    for (int q = tid; q < P*NLMAX; q += 256) {
        int p = q / NLMAX, li = q % NLMAX;
        if (li < NL) {
            const float* ap = adj + (size_t)(b*P + i0)*PL + p*L + li*4 + lpar;
            float4 v0, v1;
            v0.x = (ap[(size_t)0*PL] > 0.f) ? 1.f : 0.f;
            v0.y = (ap[(size_t)1*PL] > 0.f) ? 1.f : 0.f;
            v0.z = (ap[(size_t)2*PL] > 0.f) ? 1.f : 0.f;
            v0.w = (ap[(size_t)3*PL] > 0.f) ? 1.f : 0.f;
            v1.x = (ap[(size_t)4*PL] > 0.f) ? 1.f : 0.f;
            v1.y = (ap[(size_t)5*PL] > 0.f) ? 1.f : 0.f;
            v1.z = (ap[(size_t)6*PL] > 0.f) ? 1.f : 0.f;
            v1.w = (ap[(size_t)7*PL] > 0.f) ? 1.f : 0.f;
            *(float4*)(w_lds + li*WROW + p*8)     = v0;
            *(float4*)(w_lds + li*WROW + p*8 + 4) = v1;
        }
    }
    __syncthreads();

    // ---- Phase B: M2[li] = max over unmasked j of e2s[j][li]
    if (tid < 32*NLMAX) {
        int li = tid >> 5, t = tid & 31;
        if (li < NL) {
            float mx = -INFINITY;
            for (int j = t; j < P; j += 32) {
                float v = msk[j] ? -INFINITY : e2s[j*NLMAX + li];
                mx = fmaxf(mx, v);
            }
            #pragma unroll
            for (int off = 16; off; off >>= 1)
                mx = fmaxf(mx, __shfl_down(mx, off, 32));
            if (t == 0) M2[li] = mx;
        }
    }
    __syncthreads();

    // ---- Phase C: wave jcw handles j-chunk, lane r = (li,ti) row
    {
        int jcw = tid >> 6;
        int r   = tid & 63;
        if (r < TI*NL) {
            int ti = r & 7, li = r >> 3;
            float e1v = e1s[r];
            float s0  = e1v + M2[li];
            float m   = fmaxf(s0, SLOPE*s0);   // leaky(e1+M2) == row max
            float sum = 0.f;
            float* wrow = w_lds + li*WROW + ti;
            int j0 = jcw*32;
            #pragma unroll 4
            for (int j = j0; j < j0+32; ++j) {
                float s = e1v + e2s[j*NLMAX + li];
                s = fmaxf(s, SLOPE*s);
                float ex = msk[j] ? 0.f : __expf(s - m);
                sum += ex;
                wrow[j*8] *= ex;               // adjbit * exp
            }
            psum[jcw*TI*NLMAX + r] = sum;
        }
    }
    __syncthreads();
    if (tid < TI*NL) {
        float s = psum[tid] + psum[TI*NLMAX + tid]
                + psum[2*TI*NLMAX + tid] + psum[3*TI*NLMAX + tid];
        invs[tid] = 1.f / s;
    }
    __syncthreads();

    // ---- Phase D: units = (li, h-half); 4 groups of 64 lanes; lane owns 2 h
    int g    = tid >> 6;
    int lane = tid & 63;
    for (int unit = g; unit < 2*NL; unit += 4) {
        int li = unit >> 1, hh = unit & 1;
        int l  = li*4 + lpar;
        int hb = hh*128 + lane*2;
        float2 acc[TI];
        #pragma unroll
        for (int t = 0; t < TI; ++t) { acc[t].x = 0.f; acc[t].y = 0.f; }
        const float* ap = A + ((size_t)(b*P)*L + l)*H + hb;
        const float* wp = w_lds + li*WROW;
        #pragma unroll 4
        for (int j = 0; j < P; ++j) {
            float2 a = *(const float2*)(ap + (size_t)j*(L*H));
            float4 w0 = *(const float4*)(wp + j*8);
            float4 w1 = *(const float4*)(wp + j*8 + 4);
            acc[0].x = fmaf(w0.x, a.x, acc[0].x); acc[0].y = fmaf(w0.x, a.y, acc[0].y);
            acc[1].x = fmaf(w0.y, a.x, acc[1].x); acc[1].y = fmaf(w0.y, a.y, acc[1].y);
            acc[2].x = fmaf(w0.z, a.x, acc[2].x); acc[2].y = fmaf(w0.z, a.y, acc[2].y);
            acc[3].x = fmaf(w0.w, a.x, acc[3].x); acc[3].y = fmaf(w0.w, a.y, acc[3].y);
            acc[4].x = fmaf(w1.x, a.x, acc[4].x); acc[4].y = fmaf(w1.x, a.y, acc[4].y);
            acc[5].x = fmaf(w1.y, a.x, acc[5].x); acc[5].y = fmaf(w1.y, a.y, acc[5].y);
            acc[6].x = fmaf(w1.z, a.x, acc[6].x); acc[6].y = fmaf(w1.z, a.y, acc[6].y);
            acc[7].x = fmaf(w1.w, a.x, acc[7].x); acc[7].y = fmaf(w1.w, a.y, acc[7].y);
        }
        #pragma unroll
        for (int t = 0; t < TI; ++t) {
            float inv = invs[li*8 + t];
            float2 o;
            o.x = 1.f/(1.f + __expf(-acc[t].x*inv));
            o.y = 1.f/(1.f + __expf(-acc[t].y*inv));
            *(float2*)(out + ((size_t)(b*P + i0 + t)*L + l)*H + hb) = o;
        }
    }
}

extern "C" void kernel_launch(void* const* d_in, const int* in_sizes, int n_in,
                              void* d_out, int out_size, void* d_ws, size_t ws_size,
                              hipStream_t stream) {
    const float* agents = (const float*)d_in[0];
    const float* adj    = (const float*)d_in[1];
    const void*  mask   = d_in[2];
    const float* W1     = (const float*)d_in[3];
    const float* W2     = (const float*)d_in[4];
    float* out = (float*)d_out;

    int*   flag = (int*)d_ws;
    float* u    = (float*)d_ws + 16;
    float* e1   = u + 2*H;
    float* e2   = e1 + B*P*L;

    sniff_mask<<<1, 256, 0, stream>>>((const unsigned char*)mask, flag);
    compute_u <<<1, 256, 0, stream>>>(W1, W2, u);
    compute_e <<<(B*P*L)/4, 256, 0, stream>>>(agents, u, e1, e2);
    gat_main  <<<NBLK, 256, 0, stream>>>(agents, adj, mask, e1, e2, flag, out);
}

// Round 4
// 97.563 us; speedup vs baseline: 2.7069x; 1.4787x over previous
//
#include <hip/hip_runtime.h>
#include <math.h>

#define B  32
#define P  128
#define L  19
#define H  256
#define SLOPE 0.2f
#define PL (P*L)          /* 2432 */
#define TI 8
#define NTILE (P/TI)      /* 16 */
#define NLMAX 4
#define WROW 1032         /* 128*8 + 8 pad: 16B-aligned rows, bank skew 8 */
#define NBLK (B*NTILE*5)  /* 2560 */

// ---------------------------------------------------------------------------
// Kernel 0: detect mask buffer layout (1-byte bool vs int32 0/1).
// ---------------------------------------------------------------------------
__global__ void sniff_mask(const unsigned char* __restrict__ m, int* flag) {
    __shared__ int s;
    if (threadIdx.x == 0) s = 0;
    __syncthreads();
    int acc = 0;
    for (int k = threadIdx.x; k < 1024; k += 256)
        acc |= m[4*k+1] | m[4*k+2] | m[4*k+3];
    if (acc) atomicOr(&s, 1);
    __syncthreads();
    if (threadIdx.x == 0) flag[0] = s;   // 1 => byte layout, 0 => int32 layout
}

// ---------------------------------------------------------------------------
// Kernel 1: u1[h] = sum_a W1[a,h]*W2[a],  u2[h] = sum_a W1[a,h]*W2[HA+a]
// ---------------------------------------------------------------------------
__global__ void compute_u(const float* __restrict__ W1,
                          const float* __restrict__ W2,
                          float* __restrict__ u) {
    int h = threadIdx.x;
    float s1 = 0.f, s2 = 0.f;
    for (int a = 0; a < 128; ++a) {
        float w = W1[a*H + h];
        s1 += w * W2[a];
        s2 += w * W2[128 + a];
    }
    u[h]     = s1;
    u[H + h] = s2;
}

// ---------------------------------------------------------------------------
// Kernel 2: e1[row]=agents[row,:]·u1, e2[row]=agents[row,:]·u2
// ---------------------------------------------------------------------------
__global__ __launch_bounds__(256) void compute_e(const float* __restrict__ A,
                                                 const float* __restrict__ u,
                                                 float* __restrict__ e1,
                                                 float* __restrict__ e2) {
    int wid  = threadIdx.x >> 6;
    int lane = threadIdx.x & 63;
    int row  = blockIdx.x * 4 + wid;
    const float4 a  = *(const float4*)(A + (size_t)row*H + lane*4);
    const float4 u1 = *(const float4*)(u + lane*4);
    const float4 u2 = *(const float4*)(u + H + lane*4);
    float s1 = a.x*u1.x + a.y*u1.y + a.z*u1.z + a.w*u1.w;
    float s2 = a.x*u2.x + a.y*u2.y + a.z*u2.z + a.w*u2.w;
    #pragma unroll
    for (int off = 32; off; off >>= 1) {
        s1 += __shfl_down(s1, off, 64);
        s2 += __shfl_down(s2, off, 64);
    }
    if (lane == 0) { e1[row] = s1; e2[row] = s2; }
}

// ---------------------------------------------------------------------------
// Kernel 3: block = (b, 8-row i-tile, l mod-5 slice). NL = 4 (3 for lpar==4).
// A0: ballot-compact unmasked j -> joff[] (= p*L*H), M = count.
//     Masked j have softmax weight exactly 0 (exp underflow) -> skip exactly.
// A1: stage adjbit (f32 0/1) for compacted j, e2 slice, e1 slice.
// B : M2[li] = max_jj e2c  (leaky_relu monotone -> closed-form row max)
// C : w = adjbit * exp(leaky(e1+e2)-m), partial sums; 1/sum deferred
//     to epilogue (linearity).
// D : per (li,h-half) unit (2 per wave-group, balanced); lane owns 2 h,
//     acc float2[8], 16 FMA per compacted j.
// LDS ~19.9 KB -> 7 blocks/CU -> 28 waves.
// ---------------------------------------------------------------------------
__global__ __launch_bounds__(256, 7) void gat_main(
    const float* __restrict__ A,
    const float* __restrict__ adj,
    const void*  __restrict__ maskp,
    const float* __restrict__ e1,
    const float* __restrict__ e2,
    const int*   __restrict__ flagp,
    float* __restrict__ out)
{
    __shared__ float w_lds[NLMAX*WROW];      // [li][jj*8+ti]  16512 B
    __shared__ float e2c[P*NLMAX];           // [jj*4+li]       2048 B
    __shared__ int   joff[P];                // p*L*H            512 B
    __shared__ float e1s[TI*NLMAX];          // [li*8+ti]
    __shared__ float invs[TI*NLMAX];
    __shared__ float M2[NLMAX];
    __shared__ float psum[4*TI*NLMAX];
    __shared__ int   cnt[2];

    // XCD swizzle: all 80 blocks of one b share an XCD (agents[b] L2-resident)
    int w     = blockIdx.x;
    int xcd   = w & 7;
    int idx   = w >> 3;
    int lpar  = idx % 5;
    int rest  = idx / 5;
    int itile = rest & (NTILE-1);
    int bg    = rest >> 4;                   // 0..3
    int b     = bg*8 + xcd;
    int i0    = itile*TI;
    int tid   = threadIdx.x;
    int NL    = (lpar == 4) ? 3 : 4;

    // ---- A0: compact unmasked j
    int flag = flagp[0];
    int keep = 0;
    if (tid < P) {
        int mv;
        if (flag) mv = (((const unsigned char*)maskp)[b*P + tid] != 0);
        else      mv = (((const int*)maskp)[b*P + tid] != 0);
        keep = !mv;
    }
    unsigned long long bal = __ballot(keep);
    if (tid == 0) cnt[0] = (int)__popcll(bal);
    __syncthreads();
    if (keep) {
        int lane = tid & 63;
        int pos  = (int)__popcll(bal & ((1ull << lane) - 1ull));
        if (tid >= 64) pos += cnt[0];
        joff[pos] = tid * (L*H);             // j == tid here
    }
    if (tid == 64) cnt[1] = cnt[0] + (int)__popcll(bal);
    __syncthreads();
    int M = cnt[1];

    // ---- A1: staging (compacted)
    for (int q = tid; q < M*NLMAX; q += 256) {
        int jj = q >> 2, li = q & 3;
        if (li < NL) {
            int pL = joff[jj] >> 8;          // p*L  (L*H == 4864 = 19<<8)
            e2c[q] = e2[b*PL + pL + lpar + 5*li];
        }
    }
    if (tid < TI*NL) {
        int ti = tid & 7, li = tid >> 3;
        e1s[tid] = e1[(b*P + i0 + ti)*L + lpar + 5*li];
    }
    for (int q = tid; q < M*NLMAX; q += 256) {
        int jj = q >> 2, li = q & 3;
        if (li < NL) {
            int pL = joff[jj] >> 8;
            const float* ap = adj + (size_t)(b*P + i0)*PL + pL + lpar + 5*li;
            float4 v0, v1;
            v0.x = (ap[(size_t)0*PL] > 0.f) ? 1.f : 0.f;
            v0.y = (ap[(size_t)1*PL] > 0.f) ? 1.f : 0.f;
            v0.z = (ap[(size_t)2*PL] > 0.f) ? 1.f : 0.f;
            v0.w = (ap[(size_t)3*PL] > 0.f) ? 1.f : 0.f;
            v1.x = (ap[(size_t)4*PL] > 0.f) ? 1.f : 0.f;
            v1.y = (ap[(size_t)5*PL] > 0.f) ? 1.f : 0.f;
            v1.z = (ap[(size_t)6*PL] > 0.f) ? 1.f : 0.f;
            v1.w = (ap[(size_t)7*PL] > 0.f) ? 1.f : 0.f;
            *(float4*)(w_lds + li*WROW + jj*8)     = v0;
            *(float4*)(w_lds + li*WROW + jj*8 + 4) = v1;
        }
    }
    __syncthreads();

    // ---- B: M2[li] = max over compacted j of e2c
    if (tid < 32*NLMAX) {
        int li = tid >> 5, t = tid & 31;
        if (li < NL) {
            float mx = -INFINITY;
            for (int jj = t; jj < M; jj += 32)
                mx = fmaxf(mx, e2c[jj*4 + li]);
            #pragma unroll
            for (int off = 16; off; off >>= 1)
                mx = fmaxf(mx, __shfl_down(mx, off, 32));
            if (t == 0) M2[li] = mx;
        }
    }
    __syncthreads();

    // ---- C: softmax numerators into w_lds, partial sums
    {
        int jcw = tid >> 6;
        int r   = tid & 63;
        if (r < TI*NL) {
            int ti = r & 7, li = r >> 3;
            float e1v = e1s[r];
            float s0  = e1v + M2[li];
            float m   = fmaxf(s0, SLOPE*s0);     // leaky(e1+M2) == row max
            float sum = 0.f;
            float* wrow = w_lds + li*WROW + ti;
            for (int jj = jcw; jj < M; jj += 4) {
                float s = e1v + e2c[jj*4 + li];
                s = fmaxf(s, SLOPE*s);
                float ex = __expf(s - m);
                sum += ex;
                wrow[jj*8] *= ex;                // adjbit * exp
            }
            psum[jcw*(TI*NLMAX) + r] = sum;
        }
    }
    __syncthreads();
    if (tid < TI*NL) {
        float s = psum[tid] + psum[TI*NLMAX + tid]
                + psum[2*TI*NLMAX + tid] + psum[3*TI*NLMAX + tid];
        invs[tid] = 1.f / s;
    }
    __syncthreads();

    // ---- D: units (li, h-half); 2 per wave-group (balanced); lane owns 2 h
    int g    = tid >> 6;
    int lane = tid & 63;
    for (int unit = g; unit < 2*NL; unit += 4) {
        int li = unit >> 1, hh = unit & 1;
        int l  = lpar + 5*li;
        int hb = hh*128 + lane*2;
        float2 acc[TI];
        #pragma unroll
        for (int t = 0; t < TI; ++t) { acc[t].x = 0.f; acc[t].y = 0.f; }
        const float* ap = A + (size_t)b*(P*L*H) + (size_t)l*H + hb;
        const float* wp = w_lds + li*WROW;
        #pragma unroll 4
        for (int jj = 0; jj < M; ++jj) {
            float2 a = *(const float2*)(ap + joff[jj]);
            float4 w0 = *(const float4*)(wp + jj*8);
            float4 w1 = *(const float4*)(wp + jj*8 + 4);
            acc[0].x = fmaf(w0.x, a.x, acc[0].x); acc[0].y = fmaf(w0.x, a.y, acc[0].y);
            acc[1].x = fmaf(w0.y, a.x, acc[1].x); acc[1].y = fmaf(w0.y, a.y, acc[1].y);
            acc[2].x = fmaf(w0.z, a.x, acc[2].x); acc[2].y = fmaf(w0.z, a.y, acc[2].y);
            acc[3].x = fmaf(w0.w, a.x, acc[3].x); acc[3].y = fmaf(w0.w, a.y, acc[3].y);
            acc[4].x = fmaf(w1.x, a.x, acc[4].x); acc[4].y = fmaf(w1.x, a.y, acc[4].y);
            acc[5].x = fmaf(w1.y, a.x, acc[5].x); acc[5].y = fmaf(w1.y, a.y, acc[5].y);
            acc[6].x = fmaf(w1.z, a.x, acc[6].x); acc[6].y = fmaf(w1.z, a.y, acc[6].y);
            acc[7].x = fmaf(w1.w, a.x, acc[7].x); acc[7].y = fmaf(w1.w, a.y, acc[7].y);
        }
        #pragma unroll
        for (int t = 0; t < TI; ++t) {
            float inv = invs[li*8 + t];
            float2 o;
            o.x = 1.f/(1.f + __expf(-acc[t].x*inv));
            o.y = 1.f/(1.f + __expf(-acc[t].y*inv));
            *(float2*)(out + ((size_t)(b*P + i0 + t)*L + l)*H + hb) = o;
        }
    }
}

extern "C" void kernel_launch(void* const* d_in, const int* in_sizes, int n_in,
                              void* d_out, int out_size, void* d_ws, size_t ws_size,
                              hipStream_t stream) {
    const float* agents = (const float*)d_in[0];
    const float* adj    = (const float*)d_in[1];
    const void*  mask   = d_in[2];
    const float* W1     = (const float*)d_in[3];
    const float* W2     = (const float*)d_in[4];
    float* out = (float*)d_out;

    int*   flag = (int*)d_ws;
    float* u    = (float*)d_ws + 16;
    float* e1   = u + 2*H;
    float* e2   = e1 + B*P*L;

    sniff_mask<<<1, 256, 0, stream>>>((const unsigned char*)mask, flag);
    compute_u <<<1, 256, 0, stream>>>(W1, W2, u);
    compute_e <<<(B*P*L)/4, 256, 0, stream>>>(agents, u, e1, e2);
    gat_main  <<<NBLK, 256, 0, stream>>>(agents, adj, mask, e1, e2, flag, out);
}

// Round 6
// 81.567 us; speedup vs baseline: 3.2378x; 1.1961x over previous
//
#include <hip/hip_runtime.h>
#include <math.h>

#define B  32
#define P  128
#define L  19
#define H  256
#define SLOPE 0.2f
#define PL (P*L)          /* 2432 */
#define LH (L*H)          /* 4864 */
#define TI 16
#define NIT (P/TI)        /* 8 */
#define NBLK (B*NIT*L)    /* 4864 */

#define ABW 168           /* Ab LDS row width (u16): 128 + 40 pad = 336 B = 21*16 */
#define WW  136           /* W  LDS row width (u16): 272 B = 17*16 */

typedef __attribute__((ext_vector_type(8))) short bf16x8;
typedef __attribute__((ext_vector_type(4))) float f32x4;

__device__ inline unsigned short f32_to_bf16(float x) {
    unsigned u = __builtin_bit_cast(unsigned, x);
    unsigned r = (u + 0x7fffu + ((u >> 16) & 1u)) >> 16;
    return (unsigned short)r;
}
__device__ inline unsigned pack_bf16x2(float f0, float f1) {
    return (unsigned)f32_to_bf16(f0) | ((unsigned)f32_to_bf16(f1) << 16);
}

// ---------------------------------------------------------------------------
// Kernel 0: detect mask buffer layout (1-byte bool vs int32 0/1).
// ---------------------------------------------------------------------------
__global__ void sniff_mask(const unsigned char* __restrict__ m, int* flag) {
    __shared__ int s;
    if (threadIdx.x == 0) s = 0;
    __syncthreads();
    int acc = 0;
    for (int k = threadIdx.x; k < 1024; k += 256)
        acc |= m[4*k+1] | m[4*k+2] | m[4*k+3];
    if (acc) atomicOr(&s, 1);
    __syncthreads();
    if (threadIdx.x == 0) flag[0] = s;   // 1 => byte layout, 0 => int32 layout
}

// ---------------------------------------------------------------------------
// Kernel 1: u1[h] = sum_a W1[a,h]*W2[a],  u2[h] = sum_a W1[a,h]*W2[HA+a]
// ---------------------------------------------------------------------------
__global__ void compute_u(const float* __restrict__ W1,
                          const float* __restrict__ W2,
                          float* __restrict__ u) {
    int h = threadIdx.x;
    float s1 = 0.f, s2 = 0.f;
    for (int a = 0; a < 128; ++a) {
        float w = W1[a*H + h];
        s1 += w * W2[a];
        s2 += w * W2[128 + a];
    }
    u[h]     = s1;
    u[H + h] = s2;
}

// ---------------------------------------------------------------------------
// Kernel 2: e1[row]=agents[row,:]·u1, e2[row]=agents[row,:]·u2
// ---------------------------------------------------------------------------
__global__ __launch_bounds__(256) void compute_e(const float* __restrict__ A,
                                                 const float* __restrict__ u,
                                                 float* __restrict__ e1,
                                                 float* __restrict__ e2) {
    int wid  = threadIdx.x >> 6;
    int lane = threadIdx.x & 63;
    int row  = blockIdx.x * 4 + wid;
    const float4 a  = *(const float4*)(A + (size_t)row*H + lane*4);
    const float4 u1 = *(const float4*)(u + lane*4);
    const float4 u2 = *(const float4*)(u + H + lane*4);
    float s1 = a.x*u1.x + a.y*u1.y + a.z*u1.z + a.w*u1.w;
    float s2 = a.x*u2.x + a.y*u2.y + a.z*u2.z + a.w*u2.w;
    #pragma unroll
    for (int off = 32; off; off >>= 1) {
        s1 += __shfl_down(s1, off, 64);
        s2 += __shfl_down(s2, off, 64);
    }
    if (lane == 0) { e1[row] = s1; e2[row] = s2; }
}

// ---------------------------------------------------------------------------
// Kernel 3: block = (b, 16-row i-tile, l). MFMA weighted sum.
//  A0: ballot-compact unmasked j -> joff (padded to Kn*32 with dup of last).
//  Softmax: thread (i=tid>>4, jl=tid&15); closed-form row max via monotone
//           leaky + shfl reduce; W[i][jj] = bf16(adjbit*ex);
//           1/sum deferred to epilogue (linearity). Zero-pad W cols [M,Kn*32).
//  Stage:   agents quarter [64h][jj] -> bf16 LDS, coalesced f32 loads
//           (lane=h), packed pairs, b128 writes (slot-uniform, conflict-free).
//  MFMA:    D[16i x 16h] += W-frag x Ab-frag per 32-j step; per wave 1 htile
//           per quarter; C/D: col=lane&15, row=(lane>>4)*4+reg.
//  Epilogue: sigmoid(acc*inv) -> f32 stores.
// LDS ~27 KB -> 5 blocks/CU.
// ---------------------------------------------------------------------------
__global__ __launch_bounds__(256, 5) void gat_main(
    const float* __restrict__ A,
    const float* __restrict__ adj,
    const void*  __restrict__ maskp,
    const float* __restrict__ e1,
    const float* __restrict__ e2,
    const int*   __restrict__ flagp,
    float* __restrict__ out)
{
    __shared__ unsigned short Ab[64*ABW];   // 21504 B  [h_loc][jj]
    __shared__ unsigned short W[TI*WW];     // 4352 B   [i][jj]
    __shared__ float e2c[P];
    __shared__ int   joff[P];
    __shared__ float invs[TI];
    __shared__ int   cnt[2];

    // XCD swizzle: same-b blocks contiguous per XCD (agents[b] ~2.4MB in L2)
    int w   = blockIdx.x;
    int xcd = w & 7;
    int q   = w >> 3;
    int it  = q & 7;
    int r   = q >> 3;            // 0..75
    int l   = r % 19;
    int bg  = r / 19;            // 0..3
    int b   = bg*8 + xcd;
    int i0  = it*TI;
    int tid = threadIdx.x;

    // ---- A0: compact unmasked j
    int flag = flagp[0];
    int keep = 0;
    if (tid < P) {
        int mv = flag ? (((const unsigned char*)maskp)[b*P + tid] != 0)
                      : (((const int*)maskp)[b*P + tid] != 0);
        keep = !mv;
    }
    unsigned long long bal = __ballot(keep);
    if (tid == 0)  cnt[0] = (int)__popcll(bal);
    if (tid == 64) cnt[1] = (int)__popcll(bal);
    __syncthreads();                               // S1
    int M  = cnt[0] + cnt[1];
    int Kn = (M + 31) >> 5;                        // 32-chunk count
    if (keep) {
        int lane = tid & 63;
        int pos  = (int)__popcll(bal & ((1ull << lane) - 1ull));
        if (tid >= 64) pos += cnt[0];
        joff[pos] = tid;
    }
    __syncthreads();                               // S2
    if (tid >= M && tid < Kn*32) joff[tid] = joff[M-1];   // pad rows (dup)
    if (tid < M) e2c[tid] = e2[b*PL + joff[tid]*L + l];
    __syncthreads();                               // S3

    // stage one 64-h quarter of agents (bf16, compacted j) into Ab
    auto stage = [&](int qh) {
        int h_s = tid & 63;
        int jq  = tid >> 6;
        const float* abase = A + (size_t)b*(P*LH) + (size_t)l*H + qh*64 + h_s;
        for (int o = jq; o < Kn*4; o += 4) {       // octets of 8 jj
            unsigned pk[4];
            #pragma unroll
            for (int t = 0; t < 4; ++t) {
                float f0 = abase[(size_t)joff[o*8 + 2*t]     * LH];
                float f1 = abase[(size_t)joff[o*8 + 2*t + 1] * LH];
                pk[t] = pack_bf16x2(f0, f1);
            }
            *(uint4*)&Ab[h_s*ABW + o*8] = make_uint4(pk[0], pk[1], pk[2], pk[3]);
        }
    };

    stage(0);   // quarter 0 overlaps softmax (disjoint LDS regions)

    // ---- softmax -> W (bf16), invs
    {
        int i  = tid >> 4;
        int jl = tid & 15;
        float e1v = e1[(b*P + i0 + i)*L + l];
        float mx = -INFINITY;
        for (int jj = jl; jj < M; jj += 16) mx = fmaxf(mx, e2c[jj]);
        #pragma unroll
        for (int off = 8; off; off >>= 1) mx = fmaxf(mx, __shfl_xor(mx, off, 16));
        float s0 = e1v + mx;
        float m  = fmaxf(s0, SLOPE*s0);            // leaky(e1+max e2) == row max
        const float* arow = adj + ((size_t)(b*P + i0 + i)*P)*L + l;
        float sum = 0.f;
        for (int jj = jl; jj < M; jj += 16) {
            int j   = joff[jj];
            float av = arow[(size_t)j*L];
            float s  = e1v + e2c[jj];
            s = fmaxf(s, SLOPE*s);
            float ex = __expf(s - m);
            sum += ex;
            float wv = (av > 0.f) ? ex : 0.f;
            W[i*WW + jj] = f32_to_bf16(wv);
        }
        for (int jj = M + jl; jj < Kn*32; jj += 16) W[i*WW + jj] = 0;  // K pad
        #pragma unroll
        for (int off = 8; off; off >>= 1) sum += __shfl_xor(sum, off, 16);
        if (jl == 0) invs[i] = 1.f / sum;
    }
    __syncthreads();                               // S4: W, invs, Ab q0 ready

    // ---- MFMA + epilogue per 64-h quarter
    int lane = tid & 63;
    int wvq  = tid >> 6;          // wave -> htile within quarter
    int fr   = lane & 15;
    int kc   = lane >> 4;

    bf16x8 af[4];
    #pragma unroll
    for (int ks = 0; ks < 4; ++ks)
        if (ks < Kn) af[ks] = *(const bf16x8*)&W[fr*WW + ks*32 + kc*8];

    float invq[4];
    #pragma unroll
    for (int rr = 0; rr < 4; ++rr) invq[rr] = invs[kc*4 + rr];

    for (int qh = 0; qh < 4; ++qh) {
        if (qh > 0) {
            __syncthreads();      // mfma reads of previous quarter done
            stage(qh);
            __syncthreads();      // new quarter staged
        }
        f32x4 acc = {0.f, 0.f, 0.f, 0.f};
        #pragma unroll
        for (int ks = 0; ks < 4; ++ks) {
            if (ks < Kn) {
                bf16x8 bf = *(const bf16x8*)&Ab[(wvq*16 + fr)*ABW + ks*32 + kc*8];
                acc = __builtin_amdgcn_mfma_f32_16x16x32_bf16(af[ks], bf, acc, 0, 0, 0);
            }
        }
        int hcol = qh*64 + wvq*16 + fr;
        float* op = out + ((size_t)(b*P + i0 + kc*4)*L + l)*H + hcol;
        #pragma unroll
        for (int rr = 0; rr < 4; ++rr) {
            float x = acc[rr] * invq[rr];
            op[(size_t)rr*LH] = 1.f/(1.f + __expf(-x));
        }
    }
}

extern "C" void kernel_launch(void* const* d_in, const int* in_sizes, int n_in,
                              void* d_out, int out_size, void* d_ws, size_t ws_size,
                              hipStream_t stream) {
    const float* agents = (const float*)d_in[0];
    const float* adj    = (const float*)d_in[1];
    const void*  mask   = d_in[2];
    const float* W1     = (const float*)d_in[3];
    const float* W2     = (const float*)d_in[4];
    float* out = (float*)d_out;

    int*   flag = (int*)d_ws;
    float* u    = (float*)d_ws + 16;
    float* e1   = u + 2*H;
    float* e2   = e1 + B*P*L;

    sniff_mask<<<1, 256, 0, stream>>>((const unsigned char*)mask, flag);
    compute_u <<<1, 256, 0, stream>>>(W1, W2, u);
    compute_e <<<(B*P*L)/4, 256, 0, stream>>>(agents, u, e1, e2);
    gat_main  <<<NBLK, 256, 0, stream>>>(agents, adj, mask, e1, e2, flag, out);
}

// Round 7
// 68.733 us; speedup vs baseline: 3.8424x; 1.1867x over previous
//
#include <hip/hip_runtime.h>
#include <math.h>

#define B  32
#define P  128
#define L  19
#define H  256
#define SLOPE 0.2f
#define PL (P*L)          /* 2432 */
#define LH (L*H)          /* 4864 */
#define NBLK (B*L)        /* 608 */

#define WW  136           /* W  LDS row width (u16): 272 B, quad-stride 17 (odd) */
#define ABW 136           /* Ab LDS row width (u16) */

typedef __attribute__((ext_vector_type(8))) short bf16x8;
typedef __attribute__((ext_vector_type(4))) float f32x4;

__device__ inline unsigned short f32_to_bf16(float x) {
    unsigned u = __builtin_bit_cast(unsigned, x);
    unsigned r = (u + 0x7fffu + ((u >> 16) & 1u)) >> 16;
    return (unsigned short)r;
}
__device__ inline unsigned pack_bf16x2(float f0, float f1) {
    return (unsigned)f32_to_bf16(f0) | ((unsigned)f32_to_bf16(f1) << 16);
}

// ---------------------------------------------------------------------------
// Kernel 0: detect mask buffer layout (1-byte bool vs int32 0/1).
// ---------------------------------------------------------------------------
__global__ void sniff_mask(const unsigned char* __restrict__ m, int* flag) {
    __shared__ int s;
    if (threadIdx.x == 0) s = 0;
    __syncthreads();
    int acc = 0;
    for (int k = threadIdx.x; k < 1024; k += 256)
        acc |= m[4*k+1] | m[4*k+2] | m[4*k+3];
    if (acc) atomicOr(&s, 1);
    __syncthreads();
    if (threadIdx.x == 0) flag[0] = s;   // 1 => byte layout, 0 => int32 layout
}

// ---------------------------------------------------------------------------
// Kernel 1: u1[h] = sum_a W1[a,h]*W2[a],  u2[h] = sum_a W1[a,h]*W2[HA+a]
// ---------------------------------------------------------------------------
__global__ void compute_u(const float* __restrict__ W1,
                          const float* __restrict__ W2,
                          float* __restrict__ u) {
    int h = threadIdx.x;
    float s1 = 0.f, s2 = 0.f;
    for (int a = 0; a < 128; ++a) {
        float w = W1[a*H + h];
        s1 += w * W2[a];
        s2 += w * W2[128 + a];
    }
    u[h]     = s1;
    u[H + h] = s2;
}

// ---------------------------------------------------------------------------
// Kernel 2: e1[row]=agents[row,:]·u1, e2[row]=agents[row,:]·u2  (HBM floor)
// ---------------------------------------------------------------------------
__global__ __launch_bounds__(256) void compute_e(const float* __restrict__ A,
                                                 const float* __restrict__ u,
                                                 float* __restrict__ e1,
                                                 float* __restrict__ e2) {
    int wid  = threadIdx.x >> 6;
    int lane = threadIdx.x & 63;
    int row  = blockIdx.x * 4 + wid;
    const float4 a  = *(const float4*)(A + (size_t)row*H + lane*4);
    const float4 u1 = *(const float4*)(u + lane*4);
    const float4 u2 = *(const float4*)(u + H + lane*4);
    float s1 = a.x*u1.x + a.y*u1.y + a.z*u1.z + a.w*u1.w;
    float s2 = a.x*u2.x + a.y*u2.y + a.z*u2.z + a.w*u2.w;
    #pragma unroll
    for (int off = 32; off; off >>= 1) {
        s1 += __shfl_down(s1, off, 64);
        s2 += __shfl_down(s2, off, 64);
    }
    if (lane == 0) { e1[row] = s1; e2[row] = s2; }
}

// ---------------------------------------------------------------------------
// Kernel 2b: pack adj>0 into bitmask  bits[b][l][i][jw], jw = j/32.
// Coalesced float4 reads of adj; bit assembly via LDS flags.
// ---------------------------------------------------------------------------
__global__ __launch_bounds__(128) void adj_bits_k(const float* __restrict__ adj,
                                                  unsigned* __restrict__ bits) {
    __shared__ unsigned char f[PL];
    int blk = blockIdx.x;            // b*P + i
    int b = blk >> 7, i = blk & 127;
    const float4* row = (const float4*)(adj + (size_t)blk * PL);
    for (int q = threadIdx.x; q < PL/4; q += 128) {
        float4 v = row[q];
        f[q*4]   = v.x > 0.f;
        f[q*4+1] = v.y > 0.f;
        f[q*4+2] = v.z > 0.f;
        f[q*4+3] = v.w > 0.f;
    }
    __syncthreads();
    int t = threadIdx.x;
    if (t < 76) {
        int l = t >> 2, jw = t & 3;
        unsigned wv = 0;
        #pragma unroll
        for (int k = 0; k < 32; ++k)
            wv |= (unsigned)f[(jw*32 + k)*L + l] << k;
        bits[(((size_t)b*L + l)*P + i)*4 + jw] = wv;
    }
}

// ---------------------------------------------------------------------------
// Kernel 3: block = (b, l), 512 threads, all 128 i rows.
//  - ballot-compact unmasked j (exact: masked weights are exactly 0)
//  - softmax: 4 threads/row, closed-form row max (leaky monotone), bit test
//    from bitmask; W[i][jj] bf16; 1/sum deferred to epilogue (linearity)
//  - agents staged once per (b,l) in 32-h eighths (bf16), wave w owns i-tile
//    w, its W-fragments persist in VGPRs across all 8 eighths
//  - MFMA 16x16x32; C/D col=lane&15 (h), row=(lane>>4)*4+rr (i)
// LDS ~47.6 KB -> 3 blocks/CU -> all 608 blocks resident.
// ---------------------------------------------------------------------------
__global__ __launch_bounds__(512, 6) void gat_main(
    const float* __restrict__ A,
    const unsigned* __restrict__ bits,
    const void*  __restrict__ maskp,
    const float* __restrict__ e1,
    const float* __restrict__ e2,
    const int*   __restrict__ flagp,
    float* __restrict__ out)
{
    __shared__ unsigned short W[P*WW];      // 34816 B  [i][jj]
    __shared__ unsigned short Ab[32*ABW];   //  8704 B  [h_loc][jj]
    __shared__ unsigned bitw[P*4];          //  2048 B
    __shared__ float e2c[P];
    __shared__ float e1s[P];
    __shared__ float invs[P];
    __shared__ int   joff[P];
    __shared__ int   cnt[2];

    // XCD swizzle: 608 = 76*8; same-b blocks land on one XCD.
    int w   = blockIdx.x;
    int xcd = w & 7;
    int q   = w >> 3;            // 0..75
    int l   = q % 19;
    int bg  = q / 19;            // 0..3
    int b   = bg*8 + xcd;
    int tid = threadIdx.x;

    // ---- compact unmasked j; load bitmask + e1 (coalesced-ish)
    int flag = flagp[0];
    int keep = 0;
    if (tid < P) {
        int mv = flag ? (((const unsigned char*)maskp)[b*P + tid] != 0)
                      : (((const int*)maskp)[b*P + tid] != 0);
        keep = !mv;
    }
    unsigned long long bal = __ballot(keep);
    if (tid == 0)  cnt[0] = (int)__popcll(bal);
    if (tid == 64) cnt[1] = (int)__popcll(bal);
    bitw[tid] = bits[(((size_t)b*L + l)*P)*4 + tid];     // 512 words
    if (tid < P) e1s[tid] = e1[(b*P + tid)*L + l];
    __syncthreads();                               // S1
    int M  = cnt[0] + cnt[1];
    int Kn = (M + 31) >> 5;
    if (keep) {
        int lane = tid & 63;
        int pos  = (int)__popcll(bal & ((1ull << lane) - 1ull));
        if (tid >= 64) pos += cnt[0];
        joff[pos] = tid;
    }
    __syncthreads();                               // S2
    if (tid >= M && tid < Kn*32) joff[tid] = joff[M-1];   // pad (dup, W=0 kills)
    if (tid < M) e2c[tid] = e2[b*PL + joff[tid]*L + l];
    __syncthreads();                               // S3

    // stage one 32-h eighth of agents (bf16, compacted j) into Ab
    auto stage = [&](int qh) {
        int h_s = tid & 31;
        int jq  = tid >> 5;                        // 0..15
        const float* abase = A + (size_t)b*(P*LH) + (size_t)l*H + qh*32 + h_s;
        for (int o = jq; o < Kn*4; o += 16) {      // octets of 8 jj
            unsigned pk[4];
            #pragma unroll
            for (int t = 0; t < 4; ++t) {
                float f0 = abase[(size_t)joff[o*8 + 2*t]     * LH];
                float f1 = abase[(size_t)joff[o*8 + 2*t + 1] * LH];
                pk[t] = pack_bf16x2(f0, f1);
            }
            *(uint4*)&Ab[h_s*ABW + o*8] = make_uint4(pk[0], pk[1], pk[2], pk[3]);
        }
    };

    stage(0);   // overlaps softmax (disjoint LDS)

    // ---- softmax: thread (i = tid>>2, jl = tid&3), stride-4 over jj
    {
        int i  = tid >> 2;
        int jl = tid & 3;
        float e1v = e1s[i];
        float mx = -INFINITY;
        for (int jj = jl; jj < M; jj += 4) mx = fmaxf(mx, e2c[jj]);
        mx = fmaxf(mx, __shfl_xor(mx, 1, 4));
        mx = fmaxf(mx, __shfl_xor(mx, 2, 4));
        float s0 = e1v + mx;
        float m  = fmaxf(s0, SLOPE*s0);            // leaky(e1+max e2) == row max
        float sum = 0.f;
        for (int jj = jl; jj < Kn*32; jj += 4) {
            if (jj < M) {
                int j   = joff[jj];
                float s = e1v + e2c[jj];
                s = fmaxf(s, SLOPE*s);
                float ex = __expf(s - m);
                sum += ex;
                unsigned bit = (bitw[i*4 + (j >> 5)] >> (j & 31)) & 1u;
                W[i*WW + jj] = bit ? f32_to_bf16(ex) : (unsigned short)0;
            } else {
                W[i*WW + jj] = 0;                  // K pad
            }
        }
        sum += __shfl_xor(sum, 1, 4);
        sum += __shfl_xor(sum, 2, 4);
        if (jl == 0) invs[i] = 1.f / sum;
    }
    __syncthreads();                               // S4: W, invs, Ab eighth-0

    // ---- MFMA: wave w owns i-tile w; af fragments persist across eighths
    int lane = tid & 63;
    int wv   = tid >> 6;          // i-tile
    int fr   = lane & 15;
    int kc   = lane >> 4;

    bf16x8 af[4];
    #pragma unroll
    for (int ks = 0; ks < 4; ++ks)
        if (ks < Kn) af[ks] = *(const bf16x8*)&W[(wv*16 + fr)*WW + ks*32 + kc*8];

    float inv4[4];
    #pragma unroll
    for (int rr = 0; rr < 4; ++rr) inv4[rr] = invs[wv*16 + kc*4 + rr];

    for (int qh = 0; qh < 8; ++qh) {
        #pragma unroll
        for (int ht = 0; ht < 2; ++ht) {
            f32x4 acc = {0.f, 0.f, 0.f, 0.f};
            #pragma unroll
            for (int ks = 0; ks < 4; ++ks) {
                if (ks < Kn) {
                    bf16x8 bf = *(const bf16x8*)&Ab[(ht*16 + fr)*ABW + ks*32 + kc*8];
                    acc = __builtin_amdgcn_mfma_f32_16x16x32_bf16(af[ks], bf, acc, 0, 0, 0);
                }
            }
            int hcol = qh*32 + ht*16 + fr;
            float* op = out + ((size_t)(b*P + wv*16 + kc*4)*L + l)*H + hcol;
            #pragma unroll
            for (int rr = 0; rr < 4; ++rr) {
                float x = acc[rr] * inv4[rr];
                op[(size_t)rr*LH] = 1.f/(1.f + __expf(-x));
            }
        }
        if (qh < 7) {
            __syncthreads();      // all waves done reading Ab[qh]
            stage(qh + 1);
            __syncthreads();      // next eighth staged
        }
    }
}

extern "C" void kernel_launch(void* const* d_in, const int* in_sizes, int n_in,
                              void* d_out, int out_size, void* d_ws, size_t ws_size,
                              hipStream_t stream) {
    const float* agents = (const float*)d_in[0];
    const float* adj    = (const float*)d_in[1];
    const void*  mask   = d_in[2];
    const float* W1     = (const float*)d_in[3];
    const float* W2     = (const float*)d_in[4];
    float* out = (float*)d_out;

    int*      flag = (int*)d_ws;
    float*    u    = (float*)d_ws + 16;
    float*    e1   = u + 2*H;
    float*    e2   = e1 + B*P*L;
    unsigned* bits = (unsigned*)(e2 + B*P*L);     // 1.2 MB

    sniff_mask<<<1, 256, 0, stream>>>((const unsigned char*)mask, flag);
    compute_u <<<1, 256, 0, stream>>>(W1, W2, u);
    adj_bits_k<<<B*P, 128, 0, stream>>>(adj, bits);
    compute_e <<<(B*P*L)/4, 256, 0, stream>>>(agents, u, e1, e2);
    gat_main  <<<NBLK, 512, 0, stream>>>(agents, bits, mask, e1, e2, flag, out);
}

// Round 8
// 56.210 us; speedup vs baseline: 4.6984x; 1.2228x over previous
//
#include <hip/hip_runtime.h>
#include <math.h>

#define B  32
#define P  128
#define L  19
#define H  256
#define SLOPE 0.2f
#define PL (P*L)          /* 2432 */
#define LH (L*H)          /* 4864 */
#define PLH (P*L*H)
#define NBLK (B*L)        /* 608 */

#define WW  136           /* W  LDS row stride (u16), 272 B */
#define ABW 136           /* Ab LDS row stride (u16), 272 B (16B-aligned rows) */

typedef __attribute__((ext_vector_type(8))) short bf16x8;
typedef __attribute__((ext_vector_type(4))) float f32x4;

__device__ inline unsigned short f32_to_bf16(float x) {
    unsigned u = __builtin_bit_cast(unsigned, x);
    unsigned r = (u + 0x7fffu + ((u >> 16) & 1u)) >> 16;
    return (unsigned short)r;
}
__device__ inline unsigned pack_bf16x2(float f0, float f1) {
    return (unsigned)f32_to_bf16(f0) | ((unsigned)f32_to_bf16(f1) << 16);
}

// ---------------------------------------------------------------------------
// prep: blocks [0, B*P): pack adj>0 into bits[b][l][i][jw] (coalesced reads).
//       block B*P: sniff mask layout + compute u1/u2.
// ---------------------------------------------------------------------------
__global__ __launch_bounds__(256) void prep(
    const float* __restrict__ adj,
    const unsigned char* __restrict__ m,
    const float* __restrict__ W1,
    const float* __restrict__ W2,
    unsigned* __restrict__ bits,
    int* __restrict__ flag,
    float* __restrict__ u)
{
    int blk = blockIdx.x;
    if (blk < B*P) {
        __shared__ unsigned char f[PL];
        int b = blk >> 7, i = blk & 127;
        const float4* row = (const float4*)(adj + (size_t)blk * PL);
        for (int q = threadIdx.x; q < PL/4; q += 256) {
            float4 v = row[q];
            f[q*4]   = v.x > 0.f;
            f[q*4+1] = v.y > 0.f;
            f[q*4+2] = v.z > 0.f;
            f[q*4+3] = v.w > 0.f;
        }
        __syncthreads();
        int t = threadIdx.x;
        if (t < 76) {
            int l = t >> 2, jw = t & 3;
            unsigned wv = 0;
            #pragma unroll
            for (int k = 0; k < 32; ++k)
                wv |= (unsigned)f[(jw*32 + k)*L + l] << k;
            bits[(((size_t)b*L + l)*P + i)*4 + jw] = wv;
        }
    } else {
        __shared__ int s;
        if (threadIdx.x == 0) s = 0;
        __syncthreads();
        int acc = 0;
        for (int k = threadIdx.x; k < 1024; k += 256)
            acc |= m[4*k+1] | m[4*k+2] | m[4*k+3];
        if (acc) atomicOr(&s, 1);
        __syncthreads();
        if (threadIdx.x == 0) flag[0] = s;   // 1 => byte mask, 0 => int32 mask
        // u1/u2 (independent of sniff)
        int h = threadIdx.x;
        float s1 = 0.f, s2 = 0.f;
        for (int a = 0; a < 128; ++a) {
            float wv = W1[a*H + h];
            s1 += wv * W2[a];
            s2 += wv * W2[128 + a];
        }
        u[h]     = s1;
        u[H + h] = s2;
    }
}

// ---------------------------------------------------------------------------
// gat_main: block = (b, l), 512 threads.
//  P0: ballot-compact unmasked j; load bitmask + u into LDS.
//  P1: in-block e-compute: e1[j]=A_row·u1, e2[j]=A_row·u2 (4 thr/row,
//      coalesced float4 loads — replaces the separate compute_e pass).
//  P2: joff pad (dup of last; W=0 kills it), e2c gather.
//  P3: stage agents eighth 0 (bf16, XOR-swizzled chunks) || softmax
//      (closed-form row max via monotone leaky; 1/sum deferred by linearity;
//      adjacency from bitmask; W[i][jj] bf16).
//  P4: MFMA 16x16x32 per 32-h eighth; W-fragments persist in VGPRs;
//      C/D col=lane&15 (h), row=(lane>>4)*4+rr (i); sigmoid epilogue.
// LDS ~49 KB -> 3 blocks/CU; 608 blocks all resident.
// ---------------------------------------------------------------------------
__global__ __launch_bounds__(512, 6) void gat_main(
    const float* __restrict__ A,
    const unsigned* __restrict__ bits,
    const void*  __restrict__ maskp,
    const int*   __restrict__ flagp,
    const float* __restrict__ u,
    float* __restrict__ out)
{
    __shared__ unsigned short W[P*WW];      // 34816 B  [i][jj]
    __shared__ unsigned short Ab[32*ABW];   //  8704 B  [h_loc][jj] (swizzled)
    __shared__ unsigned bitw[P*4];          //  2048 B
    __shared__ __align__(16) float u_lds[2*H];  // 2048 B
    __shared__ float e2f[P];
    __shared__ float e2c[P];
    __shared__ float e1s[P];
    __shared__ float invs[P];
    __shared__ int   joff[P];
    __shared__ int   cnt[2];

    // XCD swizzle: same-b blocks land on one XCD (agents[b] ~2.4MB in L2)
    int w   = blockIdx.x;
    int xcd = w & 7;
    int q   = w >> 3;            // 0..75
    int l   = q % 19;
    int bg  = q / 19;            // 0..3
    int b   = bg*8 + xcd;
    int tid = threadIdx.x;

    // ---- P0: compact unmasked j; bitmask + u into LDS
    int flag = flagp[0];
    int keep = 0;
    if (tid < P) {
        int mv = flag ? (((const unsigned char*)maskp)[b*P + tid] != 0)
                      : (((const int*)maskp)[b*P + tid] != 0);
        keep = !mv;
    }
    unsigned long long bal = __ballot(keep);
    if (tid == 0)  cnt[0] = (int)__popcll(bal);
    if (tid == 64) cnt[1] = (int)__popcll(bal);
    bitw[tid]  = bits[(((size_t)b*L + l)*P)*4 + tid];
    u_lds[tid] = u[tid];
    __syncthreads();                               // S1
    int M  = cnt[0] + cnt[1];
    int Kn = (M + 31) >> 5;
    if (keep) {
        int lane = tid & 63;
        int pos  = (int)__popcll(bal & ((1ull << lane) - 1ull));
        if (tid >= 64) pos += cnt[0];
        joff[pos] = tid;
    }

    // ---- P1: e-compute (4 threads per row; 64 f32 each; width-4 reduce)
    {
        int j = tid >> 2, c = tid & 3;
        const float* ar = A + (size_t)b*PLH + (size_t)j*LH + (size_t)l*H;
        float s1 = 0.f, s2 = 0.f;
        #pragma unroll
        for (int t = 0; t < 16; ++t) {
            int o = (t*4 + c)*4;
            float4 a  = *(const float4*)(ar + o);
            float4 v1 = *(const float4*)&u_lds[o];
            float4 v2 = *(const float4*)&u_lds[H + o];
            s1 += a.x*v1.x + a.y*v1.y + a.z*v1.z + a.w*v1.w;
            s2 += a.x*v2.x + a.y*v2.y + a.z*v2.z + a.w*v2.w;
        }
        s1 += __shfl_xor(s1, 1, 4); s1 += __shfl_xor(s1, 2, 4);
        s2 += __shfl_xor(s2, 1, 4); s2 += __shfl_xor(s2, 2, 4);
        if (c == 0) { e1s[j] = s1; e2f[j] = s2; }
    }
    __syncthreads();                               // S2

    // ---- P2: pad joff (dup of last; its W column is 0) and gather e2c
    if (tid < P) {
        int jsrc = (tid < M) ? joff[tid] : joff[M-1];
        if (tid >= M) joff[tid] = jsrc;
        e2c[tid] = e2f[jsrc];
    }
    __syncthreads();                               // S3

    // stage one 32-h eighth of agents (bf16, compacted j) into Ab.
    // chunk-level XOR swizzle breaks the h/h+8 bank collision (16B-aligned).
    auto stage = [&](int qh) {
        int h_s = tid & 31;
        int jq  = tid >> 5;                        // 0..15
        int sw  = ((h_s >> 3) & 3) << 1;
        const float* abase = A + (size_t)b*PLH + (size_t)l*H + qh*32 + h_s;
        for (int o = jq; o < Kn*4; o += 16) {      // chunks of 8 jj
            unsigned pk[4];
            #pragma unroll
            for (int t = 0; t < 4; ++t) {
                float f0 = abase[(size_t)joff[o*8 + 2*t]     * LH];
                float f1 = abase[(size_t)joff[o*8 + 2*t + 1] * LH];
                pk[t] = pack_bf16x2(f0, f1);
            }
            *(uint4*)&Ab[h_s*ABW + (o ^ sw)*8] = make_uint4(pk[0], pk[1], pk[2], pk[3]);
        }
    };

    stage(0);   // overlaps softmax (disjoint LDS)

    // ---- P3: softmax: thread (i = tid>>2, jl = tid&3), stride-4 over jj
    {
        int i  = tid >> 2;
        int jl = tid & 3;
        float e1v = e1s[i];
        float mx = -INFINITY;
        for (int jj = jl; jj < M; jj += 4) mx = fmaxf(mx, e2c[jj]);
        mx = fmaxf(mx, __shfl_xor(mx, 1, 4));
        mx = fmaxf(mx, __shfl_xor(mx, 2, 4));
        float s0 = e1v + mx;
        float m  = fmaxf(s0, SLOPE*s0);            // leaky(e1+max e2) == row max
        float sum = 0.f;
        for (int jj = jl; jj < Kn*32; jj += 4) {
            if (jj < M) {
                int j   = joff[jj];
                float s = e1v + e2c[jj];
                s = fmaxf(s, SLOPE*s);
                float ex = __expf(s - m);
                sum += ex;
                unsigned bit = (bitw[i*4 + (j >> 5)] >> (j & 31)) & 1u;
                W[i*WW + jj] = bit ? f32_to_bf16(ex) : (unsigned short)0;
            } else {
                W[i*WW + jj] = 0;                  // K pad
            }
        }
        sum += __shfl_xor(sum, 1, 4);
        sum += __shfl_xor(sum, 2, 4);
        if (jl == 0) invs[i] = 1.f / sum;
    }
    __syncthreads();                               // S4: W, invs, Ab eighth-0

    // ---- P4: MFMA; wave wv owns i-tile wv; af fragments persist
    int lane = tid & 63;
    int wv   = tid >> 6;
    int fr   = lane & 15;
    int kc   = lane >> 4;

    bf16x8 af[4];
    #pragma unroll
    for (int ks = 0; ks < 4; ++ks)
        if (ks < Kn) af[ks] = *(const bf16x8*)&W[(wv*16 + fr)*WW + ks*32 + kc*8];

    float inv4[4];
    #pragma unroll
    for (int rr = 0; rr < 4; ++rr) inv4[rr] = invs[wv*16 + kc*4 + rr];

    for (int qh = 0; qh < 8; ++qh) {
        #pragma unroll
        for (int ht = 0; ht < 2; ++ht) {
            int row = ht*16 + fr;
            int sw  = ((row >> 3) & 3) << 1;
            f32x4 acc = {0.f, 0.f, 0.f, 0.f};
            #pragma unroll
            for (int ks = 0; ks < 4; ++ks) {
                if (ks < Kn) {
                    bf16x8 bf = *(const bf16x8*)&Ab[row*ABW + ((ks*4 + kc) ^ sw)*8];
                    acc = __builtin_amdgcn_mfma_f32_16x16x32_bf16(af[ks], bf, acc, 0, 0, 0);
                }
            }
            int hcol = qh*32 + ht*16 + fr;
            float* op = out + ((size_t)(b*P + wv*16 + kc*4)*L + l)*H + hcol;
            #pragma unroll
            for (int rr = 0; rr < 4; ++rr) {
                float x = acc[rr] * inv4[rr];
                op[(size_t)rr*LH] = 1.f/(1.f + __expf(-x));
            }
        }
        if (qh < 7) {
            __syncthreads();      // all waves done reading Ab[qh]
            stage(qh + 1);
            __syncthreads();      // next eighth staged
        }
    }
}

extern "C" void kernel_launch(void* const* d_in, const int* in_sizes, int n_in,
                              void* d_out, int out_size, void* d_ws, size_t ws_size,
                              hipStream_t stream) {
    const float* agents = (const float*)d_in[0];
    const float* adj    = (const float*)d_in[1];
    const void*  mask   = d_in[2];
    const float* W1     = (const float*)d_in[3];
    const float* W2     = (const float*)d_in[4];
    float* out = (float*)d_out;

    int*      flag = (int*)d_ws;
    float*    u    = (float*)d_ws + 16;
    unsigned* bits = (unsigned*)(u + 2*H);        // 1.2 MB

    prep    <<<B*P + 1, 256, 0, stream>>>(adj, (const unsigned char*)mask,
                                          W1, W2, bits, flag, u);
    gat_main<<<NBLK, 512, 0, stream>>>(agents, bits, mask, flag, u, out);
}